// Round 4
// baseline (615.641 us; speedup 1.0000x reference)
//
#include <hip/hip_runtime.h>
#include <hip/hip_bf16.h>
#include <stdint.h>

#define BATCH 8
#define NS 1024
#define NQ 2048
#define DIM 1024

typedef __bf16 bf16x8 __attribute__((ext_vector_type(8)));
typedef float f32x4 __attribute__((ext_vector_type(4)));

__device__ __forceinline__ unsigned short f2bf(float x) {
    unsigned u = __float_as_uint(x);
    u += 0x7fffu + ((u >> 16) & 1u);   // round-to-nearest-even
    return (unsigned short)(u >> 16);
}
__device__ __forceinline__ unsigned pk2(float a, float b) {
    return (unsigned)f2bf(a) | ((unsigned)f2bf(b) << 16);
}

// async global->LDS, 16B per lane
#define GL16(gp, lp) __builtin_amdgcn_global_load_lds( \
    (__attribute__((address_space(1))) void*)(gp),     \
    (__attribute__((address_space(3))) void*)(lp), 16, 0, 0)

// ---------------------------------------------------------------------------
// Kernel 1: per-row L2 normalize -> bf16 (ws), and copy fp32 row into the
// first half of the augmented output (fused, saves a pass).
// One wave per row; lane reads 4 float4 (16 floats).
// ---------------------------------------------------------------------------
__global__ __launch_bounds__(256) void normalize_rows(
    const float* __restrict__ in, float* __restrict__ aug,
    unsigned short* __restrict__ nrm)
{
    const int w = threadIdx.x >> 6, lane = threadIdx.x & 63;
    const long long row = (long long)blockIdx.x * 4 + w;
    const float4* in4 = (const float4*)(in + row * DIM);
    float4 v[4];
    float ss = 0.f;
#pragma unroll
    for (int i = 0; i < 4; ++i) {
        v[i] = in4[i * 64 + lane];
        ss += v[i].x * v[i].x + v[i].y * v[i].y + v[i].z * v[i].z + v[i].w * v[i].w;
    }
#pragma unroll
    for (int o = 1; o < 64; o <<= 1) ss += __shfl_xor(ss, o, 64);
    const float scale = 1.0f / fmaxf(sqrtf(ss), 1e-8f);

    float4* aug4 = (float4*)(aug + row * (2 * DIM));
    ushort4* n4 = (ushort4*)(nrm + row * DIM);
#pragma unroll
    for (int i = 0; i < 4; ++i) {
        aug4[i * 64 + lane] = v[i];
        ushort4 u;
        u.x = f2bf(v[i].x * scale);
        u.y = f2bf(v[i].y * scale);
        u.z = f2bf(v[i].z * scale);
        u.w = f2bf(v[i].w * scale);
        n4[i * 64 + lane] = u;
    }
}

// ---------------------------------------------------------------------------
// Kernel 2: emb_support fp32 [B][NS][DIM] -> embT bf16 [B][DIM][NS]
// 64x64 tiles through padded LDS; both global phases coalesced.
// ---------------------------------------------------------------------------
__global__ __launch_bounds__(256) void transpose_bf16(
    const float* __restrict__ in, unsigned short* __restrict__ out)
{
    __shared__ unsigned short t[64][65];
    const int b = blockIdx.z;
    const float* src = in + (size_t)b * NS * DIM;
    unsigned short* dst = out + (size_t)b * DIM * NS;
    const int r = threadIdx.x >> 6;    // 0..3
    const int c = threadIdx.x & 63;
    const int rbase = blockIdx.y * 64, cbase = blockIdx.x * 64;
#pragma unroll
    for (int i = 0; i < 16; ++i)
        t[r + i * 4][c] = f2bf(src[(size_t)(rbase + r + i * 4) * DIM + cbase + c]);
    __syncthreads();
#pragma unroll
    for (int i = 0; i < 16; ++i)
        dst[(size_t)(cbase + r + i * 4) * NS + rbase + c] = t[c][r + i * 4];
}

// ---------------------------------------------------------------------------
// Kernel 3/5: C[M][*] = A[M][1024] @ B[1024][1024]^T  (both K-contiguous),
// m97 structure: 128x128 tile, BK=32, 4 waves (2x2), 16x16x32 bf16 MFMA,
// global_load_lds width 16 for bf16 operands. AF32: A is fp32 (the softmax
// output G), reg-staged + RNE-converted to bf16 during LDS staging.
// C write goes to column offset `coloff` with row stride `ldc` (fuses the
// augmented-concat placement).
//
// Staging arithmetic (the round-1 bug): tile = 128 rows x 32 cols bf16 =
// 8 KB; one GL16 sweep = 256 lanes x 16 B = 4 KB. So TWO GL16 per operand
// per K-step (rows gr and gr+64). Per-wave LDS dests stay linear in lane
// (byte = wave_base + lane*16), as global_load_lds requires.
// ---------------------------------------------------------------------------
template<bool AF32>
__global__ __launch_bounds__(256) void gemm_abt(
    const void* __restrict__ Ap, const unsigned short* __restrict__ Bp,
    float* __restrict__ Cp,
    long long sA, long long sB, long long sC, int ldc, int coloff)
{
    __shared__ __align__(16) unsigned short As[128 * 32];
    __shared__ __align__(16) unsigned short Bs[128 * 32];
    const int tid = threadIdx.x, lane = tid & 63;
    const int w = tid >> 6, wr = w >> 1, wc = w & 1;
    const int bz = blockIdx.z;
    const unsigned short* B = Bp + (size_t)bz * sB + (size_t)blockIdx.x * 128 * DIM;
    f32x4 acc[4][4] = {};
    const int gr = tid >> 2, gs = (tid & 3) * 8;   // staging row / 16B slot

    for (int k0 = 0; k0 < DIM; k0 += 32) {
        if (AF32) {
            const float* A = (const float*)Ap + (size_t)bz * sA + (size_t)blockIdx.y * 128 * DIM;
            const int r = tid >> 1, h = (tid & 1) * 16;
            const float4* s4 = (const float4*)(A + (size_t)r * DIM + k0 + h);
            float4 x0 = s4[0], x1 = s4[1], x2 = s4[2], x3 = s4[3];
            uint4 w0 = { pk2(x0.x, x0.y), pk2(x0.z, x0.w), pk2(x1.x, x1.y), pk2(x1.z, x1.w) };
            uint4 w1 = { pk2(x2.x, x2.y), pk2(x2.z, x2.w), pk2(x3.x, x3.y), pk2(x3.z, x3.w) };
            *(uint4*)&As[r * 32 + h] = w0;
            *(uint4*)&As[r * 32 + h + 8] = w1;
        } else {
            const unsigned short* A = (const unsigned short*)Ap + (size_t)bz * sA + (size_t)blockIdx.y * 128 * DIM;
            GL16(A + (size_t)gr * DIM + k0 + gs, As + gr * 32 + gs);
            GL16(A + (size_t)(gr + 64) * DIM + k0 + gs, As + (gr + 64) * 32 + gs);
        }
        GL16(B + (size_t)gr * DIM + k0 + gs, Bs + gr * 32 + gs);
        GL16(B + (size_t)(gr + 64) * DIM + k0 + gs, Bs + (gr + 64) * 32 + gs);
        __syncthreads();   // drains vmcnt (global_load_lds) + lgkmcnt (ds_write)

        bf16x8 a[4], b[4];
        const int ks = (lane >> 4) * 8;
#pragma unroll
        for (int m = 0; m < 4; ++m)
            a[m] = *(const bf16x8*)&As[(wr * 64 + m * 16 + (lane & 15)) * 32 + ks];
#pragma unroll
        for (int n = 0; n < 4; ++n)
            b[n] = *(const bf16x8*)&Bs[(wc * 64 + n * 16 + (lane & 15)) * 32 + ks];
#pragma unroll
        for (int m = 0; m < 4; ++m)
#pragma unroll
            for (int n = 0; n < 4; ++n)
                acc[m][n] = __builtin_amdgcn_mfma_f32_16x16x32_bf16(a[m], b[n], acc[m][n], 0, 0, 0);
        __syncthreads();
    }

    float* C = Cp + (size_t)bz * sC;
    const int rb = blockIdx.y * 128 + wr * 64 + ((lane >> 4) << 2);
    const int cb = coloff + blockIdx.x * 128 + wc * 64 + (lane & 15);
#pragma unroll
    for (int m = 0; m < 4; ++m)
#pragma unroll
        for (int n = 0; n < 4; ++n)
#pragma unroll
            for (int j = 0; j < 4; ++j)
                C[(size_t)(rb + m * 16 + j) * ldc + cb + n * 16] = acc[m][n][j];
}

// ---------------------------------------------------------------------------
// Kernel 4: in-place row softmax over 1024-wide rows (block per row).
// ---------------------------------------------------------------------------
__global__ __launch_bounds__(256) void softmax_rows(float* __restrict__ G)
{
    __shared__ float redm[4], reds[4];
    float4* p = (float4*)(G + (long long)blockIdx.x * 1024);
    const int tid = threadIdx.x, lane = tid & 63, w = tid >> 6;
    float4 v = p[tid];
    float m = fmaxf(fmaxf(v.x, v.y), fmaxf(v.z, v.w));
#pragma unroll
    for (int o = 1; o < 64; o <<= 1) m = fmaxf(m, __shfl_xor(m, o, 64));
    if (lane == 0) redm[w] = m;
    __syncthreads();
    m = fmaxf(fmaxf(redm[0], redm[1]), fmaxf(redm[2], redm[3]));
    float4 e;
    e.x = __expf(v.x - m); e.y = __expf(v.y - m);
    e.z = __expf(v.z - m); e.w = __expf(v.w - m);
    float s = e.x + e.y + e.z + e.w;
#pragma unroll
    for (int o = 1; o < 64; o <<= 1) s += __shfl_xor(s, o, 64);
    if (lane == 0) reds[w] = s;
    __syncthreads();
    s = reds[0] + reds[1] + reds[2] + reds[3];
    const float inv = 1.0f / s;
    e.x *= inv; e.y *= inv; e.z *= inv; e.w *= inv;
    p[tid] = e;
}

// ---------------------------------------------------------------------------
extern "C" void kernel_launch(void* const* d_in, const int* in_sizes, int n_in,
                              void* d_out, int out_size, void* d_ws, size_t ws_size,
                              hipStream_t stream)
{
    const float* emb_s = (const float*)d_in[0];
    const float* emb_q = (const float*)d_in[1];
    float* out = (float*)d_out;
    float* aug_s = out;                                    // [8,1024,2048]
    float* aug_q = out + (size_t)BATCH * NS * 2 * DIM;     // [8,2048,2048]
    float* G_s   = aug_q + (size_t)BATCH * NQ * 2 * DIM;   // [8,1024,1024]
    float* G_q   = G_s + (size_t)BATCH * NS * NS;          // [8,2048,1024]

    // workspace: 16MB + 32MB + 16MB = 64MB
    unsigned short* supn = (unsigned short*)d_ws;                 // bf16 [8,1024,1024]
    unsigned short* qryn = supn + (size_t)BATCH * NS * DIM;       // bf16 [8,2048,1024]
    unsigned short* embT = qryn + (size_t)BATCH * NQ * DIM;       // bf16 [8,1024(d),1024(j)]

    normalize_rows<<<BATCH * NS / 4, 256, 0, stream>>>(emb_s, aug_s, supn);
    normalize_rows<<<BATCH * NQ / 4, 256, 0, stream>>>(emb_q, aug_q, qryn);
    transpose_bf16<<<dim3(16, 16, BATCH), 256, 0, stream>>>(emb_s, embT);

    // cos matrices into the G output regions (softmaxed in-place next)
    gemm_abt<false><<<dim3(8, 8, BATCH), 256, 0, stream>>>(supn, supn, G_s,
        (long long)NS * DIM, (long long)NS * DIM, (long long)NS * NS, NS, 0);
    gemm_abt<false><<<dim3(8, 16, BATCH), 256, 0, stream>>>(qryn, supn, G_q,
        (long long)NQ * DIM, (long long)NS * DIM, (long long)NQ * NS, NS, 0);

    softmax_rows<<<BATCH * NS, 256, 0, stream>>>(G_s);
    softmax_rows<<<BATCH * NQ, 256, 0, stream>>>(G_q);

    // emb_task into augmented second halves (A = fp32 G, B = embT bf16)
    gemm_abt<true><<<dim3(8, 8, BATCH), 256, 0, stream>>>(G_s, embT, aug_s,
        (long long)NS * NS, (long long)DIM * NS, (long long)NS * 2 * DIM, 2 * DIM, DIM);
    gemm_abt<true><<<dim3(8, 16, BATCH), 256, 0, stream>>>(G_q, embT, aug_q,
        (long long)NQ * NS, (long long)DIM * NS, (long long)NQ * 2 * DIM, 2 * DIM, DIM);
}

// Round 5
// 577.917 us; speedup vs baseline: 1.0653x; 1.0653x over previous
//
#include <hip/hip_runtime.h>
#include <hip/hip_bf16.h>
#include <stdint.h>

#define BATCH 8
#define NS 1024
#define NQ 2048
#define DIM 1024

typedef __bf16 bf16x8 __attribute__((ext_vector_type(8)));
typedef float f32x4 __attribute__((ext_vector_type(4)));

__device__ __forceinline__ unsigned short f2bf(float x) {
    unsigned u = __float_as_uint(x);
    u += 0x7fffu + ((u >> 16) & 1u);   // round-to-nearest-even
    return (unsigned short)(u >> 16);
}

// async global->LDS, 16B per lane
#define GL16(gp, lp) __builtin_amdgcn_global_load_lds( \
    (__attribute__((address_space(1))) void*)(gp),     \
    (__attribute__((address_space(3))) void*)(lp), 16, 0, 0)

// ---------------------------------------------------------------------------
// Kernel 1: per-row L2 normalize -> bf16 (ws), and copy fp32 row into the
// first half of the augmented output (fused). One wave per row.
// ---------------------------------------------------------------------------
__global__ __launch_bounds__(256) void normalize_rows(
    const float* __restrict__ in, float* __restrict__ aug,
    unsigned short* __restrict__ nrm)
{
    const int w = threadIdx.x >> 6, lane = threadIdx.x & 63;
    const long long row = (long long)blockIdx.x * 4 + w;
    const float4* in4 = (const float4*)(in + row * DIM);
    float4 v[4];
    float ss = 0.f;
#pragma unroll
    for (int i = 0; i < 4; ++i) {
        v[i] = in4[i * 64 + lane];
        ss += v[i].x * v[i].x + v[i].y * v[i].y + v[i].z * v[i].z + v[i].w * v[i].w;
    }
#pragma unroll
    for (int o = 1; o < 64; o <<= 1) ss += __shfl_xor(ss, o, 64);
    const float scale = 1.0f / fmaxf(sqrtf(ss), 1e-8f);

    float4* aug4 = (float4*)(aug + row * (2 * DIM));
    ushort4* n4 = (ushort4*)(nrm + row * DIM);
#pragma unroll
    for (int i = 0; i < 4; ++i) {
        aug4[i * 64 + lane] = v[i];
        ushort4 u;
        u.x = f2bf(v[i].x * scale);
        u.y = f2bf(v[i].y * scale);
        u.z = f2bf(v[i].z * scale);
        u.w = f2bf(v[i].w * scale);
        n4[i * 64 + lane] = u;
    }
}

// ---------------------------------------------------------------------------
// Kernel 2: emb_support fp32 [B][NS][DIM] -> embT bf16 [B][DIM][NS]
// ---------------------------------------------------------------------------
__global__ __launch_bounds__(256) void transpose_bf16(
    const float* __restrict__ in, unsigned short* __restrict__ out)
{
    __shared__ unsigned short t[64][65];
    const int b = blockIdx.z;
    const float* src = in + (size_t)b * NS * DIM;
    unsigned short* dst = out + (size_t)b * DIM * NS;
    const int r = threadIdx.x >> 6;    // 0..3
    const int c = threadIdx.x & 63;
    const int rbase = blockIdx.y * 64, cbase = blockIdx.x * 64;
#pragma unroll
    for (int i = 0; i < 16; ++i)
        t[r + i * 4][c] = f2bf(src[(size_t)(rbase + r + i * 4) * DIM + cbase + c]);
    __syncthreads();
#pragma unroll
    for (int i = 0; i < 16; ++i)
        dst[(size_t)(cbase + r + i * 4) * NS + rbase + c] = t[c][r + i * 4];
}

// ---------------------------------------------------------------------------
// GEMM: C[M][*] += A[M][1024] @ B[*][1024]^T, both operands bf16 with
// K-contiguous rows of stride 1024. m97 structure: 128x128 tile, BK=32,
// 4 waves (2x2), 16x16x32 bf16 MFMA, global_load_lds width 16.
// 1D grid with bijective XCD swizzle: each XCD gets a contiguous logical
// chunk -> A/B panel reuse hits the per-XCD L2 (512-block GEMMs: one full
// batch = 2MB A + 2MB B per XCD, fits 4MB L2).
// C write goes to column offset `coloff` with row stride `ldc` (fuses the
// augmented-concat placement).
// ---------------------------------------------------------------------------
__global__ __launch_bounds__(256) void gemm_bt(
    const unsigned short* __restrict__ Ap, const unsigned short* __restrict__ Bp,
    float* __restrict__ Cp,
    long long sA, long long sB, long long sC, int nx, int ny, int ldc, int coloff)
{
    __shared__ __align__(16) unsigned short As[128 * 32];
    __shared__ __align__(16) unsigned short Bs[128 * 32];

    // XCD-aware block swizzle (nwg % 8 == 0 guaranteed by launch config)
    const int nwg = gridDim.x;
    const int cpx = nwg >> 3;
    const int orig = blockIdx.x;
    const int wg = (orig & 7) * cpx + (orig >> 3);
    const int per = nx * ny;
    const int bz = wg / per, rem = wg - bz * per;
    const int by = rem / nx, bx = rem - by * nx;

    const int tid = threadIdx.x, lane = tid & 63;
    const int w = tid >> 6, wr = w >> 1, wc = w & 1;
    const unsigned short* A = Ap + (size_t)bz * sA + (size_t)by * 128 * DIM;
    const unsigned short* B = Bp + (size_t)bz * sB + (size_t)bx * 128 * DIM;
    f32x4 acc[4][4] = {};
    const int gr = tid >> 2, gs = (tid & 3) * 8;   // staging row / 16B slot

    for (int k0 = 0; k0 < DIM; k0 += 32) {
        // tile = 128 rows x 32 cols bf16 = 8KB; one GL16 sweep = 4KB -> two per operand
        GL16(A + (size_t)gr * DIM + k0 + gs, As + gr * 32 + gs);
        GL16(A + (size_t)(gr + 64) * DIM + k0 + gs, As + (gr + 64) * 32 + gs);
        GL16(B + (size_t)gr * DIM + k0 + gs, Bs + gr * 32 + gs);
        GL16(B + (size_t)(gr + 64) * DIM + k0 + gs, Bs + (gr + 64) * 32 + gs);
        __syncthreads();   // drains vmcnt (global_load_lds)

        bf16x8 a[4], b[4];
        const int ks = (lane >> 4) * 8;
#pragma unroll
        for (int m = 0; m < 4; ++m)
            a[m] = *(const bf16x8*)&As[(wr * 64 + m * 16 + (lane & 15)) * 32 + ks];
#pragma unroll
        for (int n = 0; n < 4; ++n)
            b[n] = *(const bf16x8*)&Bs[(wc * 64 + n * 16 + (lane & 15)) * 32 + ks];
#pragma unroll
        for (int m = 0; m < 4; ++m)
#pragma unroll
            for (int n = 0; n < 4; ++n)
                acc[m][n] = __builtin_amdgcn_mfma_f32_16x16x32_bf16(a[m], b[n], acc[m][n], 0, 0, 0);
        __syncthreads();
    }

    float* C = Cp + (size_t)bz * sC;
    const int rb = by * 128 + wr * 64 + ((lane >> 4) << 2);
    const int cb = coloff + bx * 128 + wc * 64 + (lane & 15);
#pragma unroll
    for (int m = 0; m < 4; ++m)
#pragma unroll
        for (int n = 0; n < 4; ++n)
#pragma unroll
            for (int j = 0; j < 4; ++j)
                C[(size_t)(rb + m * 16 + j) * ldc + cb + n * 16] = acc[m][n][j];
}

// ---------------------------------------------------------------------------
// Softmax over 1024-wide rows, single pass: cos in [-1,1] so use constant
// shift 1.0 instead of a row-max pass (mathematically identical after
// normalization). Writes fp32 G in-place (it IS an output) and a bf16 copy
// to ws for the downstream GEMM's async A-staging.
// ---------------------------------------------------------------------------
__global__ __launch_bounds__(256) void softmax_bf(
    float* __restrict__ G, unsigned short* __restrict__ Gb)
{
    __shared__ float reds[4];
    const long long row = blockIdx.x;
    float4* p = (float4*)(G + row * 1024);
    const int tid = threadIdx.x, lane = tid & 63, w = tid >> 6;
    float4 v = p[tid];
    float4 e;
    e.x = __expf(v.x - 1.0f); e.y = __expf(v.y - 1.0f);
    e.z = __expf(v.z - 1.0f); e.w = __expf(v.w - 1.0f);
    float s = e.x + e.y + e.z + e.w;
#pragma unroll
    for (int o = 1; o < 64; o <<= 1) s += __shfl_xor(s, o, 64);
    if (lane == 0) reds[w] = s;
    __syncthreads();
    s = reds[0] + reds[1] + reds[2] + reds[3];
    const float inv = 1.0f / s;
    e.x *= inv; e.y *= inv; e.z *= inv; e.w *= inv;
    p[tid] = e;
    ushort4 u;
    u.x = f2bf(e.x); u.y = f2bf(e.y); u.z = f2bf(e.z); u.w = f2bf(e.w);
    ((ushort4*)(Gb + row * 1024))[tid] = u;
}

// ---------------------------------------------------------------------------
extern "C" void kernel_launch(void* const* d_in, const int* in_sizes, int n_in,
                              void* d_out, int out_size, void* d_ws, size_t ws_size,
                              hipStream_t stream)
{
    const float* emb_s = (const float*)d_in[0];
    const float* emb_q = (const float*)d_in[1];
    float* out = (float*)d_out;
    float* aug_s = out;                                    // [8,1024,2048]
    float* aug_q = out + (size_t)BATCH * NS * 2 * DIM;     // [8,2048,2048]
    float* G_s   = aug_q + (size_t)BATCH * NQ * 2 * DIM;   // [8,1024,1024]
    float* G_q   = G_s + (size_t)BATCH * NS * NS;          // [8,2048,1024]

    // workspace: 16+32+16 MB bf16 buffers = 134 MB total
    unsigned short* supn = (unsigned short*)d_ws;                 // bf16 [8,1024,1024]
    unsigned short* qryn = supn + (size_t)BATCH * NS * DIM;       // bf16 [8,2048,1024]
    unsigned short* embT = qryn + (size_t)BATCH * NQ * DIM;       // bf16 [8,1024(d),1024(j)]
    // bf16 G copies REUSE supn/qryn (dead after the cos GEMMs; sizes match exactly)
    unsigned short* Gs_bf = supn;
    unsigned short* Gq_bf = qryn;

    normalize_rows<<<BATCH * NS / 4, 256, 0, stream>>>(emb_s, aug_s, supn);
    normalize_rows<<<BATCH * NQ / 4, 256, 0, stream>>>(emb_q, aug_q, qryn);
    transpose_bf16<<<dim3(16, 16, BATCH), 256, 0, stream>>>(emb_s, embT);

    // cos matrices into the G output regions (softmaxed in-place next)
    gemm_bt<<<8 * 8 * BATCH, 256, 0, stream>>>(supn, supn, G_s,
        (long long)NS * DIM, (long long)NS * DIM, (long long)NS * NS, 8, 8, NS, 0);
    gemm_bt<<<8 * 16 * BATCH, 256, 0, stream>>>(qryn, supn, G_q,
        (long long)NQ * DIM, (long long)NS * DIM, (long long)NQ * NS, 8, 16, NS, 0);

    softmax_bf<<<BATCH * NS, 256, 0, stream>>>(G_s, Gs_bf);
    softmax_bf<<<BATCH * NQ, 256, 0, stream>>>(G_q, Gq_bf);

    // emb_task into augmented second halves (A = bf16 G, B = embT bf16)
    gemm_bt<<<8 * 8 * BATCH, 256, 0, stream>>>(Gs_bf, embT, aug_s,
        (long long)NS * NS, (long long)DIM * NS, (long long)NS * 2 * DIM, 8, 8, 2 * DIM, DIM);
    gemm_bt<<<8 * 16 * BATCH, 256, 0, stream>>>(Gq_bf, embT, aug_q,
        (long long)NQ * NS, (long long)DIM * NS, (long long)NQ * 2 * DIM, 8, 16, 2 * DIM, DIM);
}

// Round 6
// 562.142 us; speedup vs baseline: 1.0952x; 1.0281x over previous
//
#include <hip/hip_runtime.h>
#include <hip/hip_bf16.h>
#include <stdint.h>

#define BATCH 8
#define NS 1024
#define NQ 2048
#define DIM 1024

typedef __bf16 bf16x8 __attribute__((ext_vector_type(8)));
typedef float f32x4 __attribute__((ext_vector_type(4)));

__device__ __forceinline__ unsigned short f2bf(float x) {
    unsigned u = __float_as_uint(x);
    u += 0x7fffu + ((u >> 16) & 1u);   // round-to-nearest-even
    return (unsigned short)(u >> 16);
}

// async global->LDS, 16B per lane
#define GL16(gp, lp) __builtin_amdgcn_global_load_lds( \
    (__attribute__((address_space(1))) void*)(gp),     \
    (__attribute__((address_space(3))) void*)(lp), 16, 0, 0)

// ---------------------------------------------------------------------------
// Kernel 1: per-row L2 normalize -> bf16 (ws), and copy fp32 row into the
// first half of the augmented output (fused). One wave per row.
// ---------------------------------------------------------------------------
__global__ __launch_bounds__(256) void normalize_rows(
    const float* __restrict__ in, float* __restrict__ aug,
    unsigned short* __restrict__ nrm)
{
    const int w = threadIdx.x >> 6, lane = threadIdx.x & 63;
    const long long row = (long long)blockIdx.x * 4 + w;
    const float4* in4 = (const float4*)(in + row * DIM);
    float4 v[4];
    float ss = 0.f;
#pragma unroll
    for (int i = 0; i < 4; ++i) {
        v[i] = in4[i * 64 + lane];
        ss += v[i].x * v[i].x + v[i].y * v[i].y + v[i].z * v[i].z + v[i].w * v[i].w;
    }
#pragma unroll
    for (int o = 1; o < 64; o <<= 1) ss += __shfl_xor(ss, o, 64);
    const float scale = 1.0f / fmaxf(sqrtf(ss), 1e-8f);

    float4* aug4 = (float4*)(aug + row * (2 * DIM));
    ushort4* n4 = (ushort4*)(nrm + row * DIM);
#pragma unroll
    for (int i = 0; i < 4; ++i) {
        aug4[i * 64 + lane] = v[i];
        ushort4 u;
        u.x = f2bf(v[i].x * scale);
        u.y = f2bf(v[i].y * scale);
        u.z = f2bf(v[i].z * scale);
        u.w = f2bf(v[i].w * scale);
        n4[i * 64 + lane] = u;
    }
}

// ---------------------------------------------------------------------------
// Kernel 2: emb_support fp32 [B][NS][DIM] -> embT bf16 [B][DIM][NS]
// ---------------------------------------------------------------------------
__global__ __launch_bounds__(256) void transpose_bf16(
    const float* __restrict__ in, unsigned short* __restrict__ out)
{
    __shared__ unsigned short t[64][65];
    const int b = blockIdx.z;
    const float* src = in + (size_t)b * NS * DIM;
    unsigned short* dst = out + (size_t)b * DIM * NS;
    const int r = threadIdx.x >> 6;    // 0..3
    const int c = threadIdx.x & 63;
    const int rbase = blockIdx.y * 64, cbase = blockIdx.x * 64;
#pragma unroll
    for (int i = 0; i < 16; ++i)
        t[r + i * 4][c] = f2bf(src[(size_t)(rbase + r + i * 4) * DIM + cbase + c]);
    __syncthreads();
#pragma unroll
    for (int i = 0; i < 16; ++i)
        dst[(size_t)(cbase + r + i * 4) * NS + rbase + c] = t[c][r + i * 4];
}

// ---------------------------------------------------------------------------
// GEMM: C[M][*] = A[M][1024] @ B[*][1024]^T, both bf16, K-contiguous rows.
// 128x128 tile, BK=32, 4 waves (2x2), 16x16x32 bf16 MFMA.
// ROUND-5 CHANGE: 2-phase double-buffered LDS pipeline (T3 minimum form):
// next tile's global_load_lds is issued BEFORE this tile's ds_read+MFMA,
// one barrier per K-iteration. Loads fly under the compute phase instead
// of being drained immediately (the 1-phase structure's ~70% stall).
// LDS 2x16KB = 32KB -> still 5 blocks/CU.
// ---------------------------------------------------------------------------
__global__ __launch_bounds__(256) void gemm_bt(
    const unsigned short* __restrict__ Ap, const unsigned short* __restrict__ Bp,
    float* __restrict__ Cp,
    long long sA, long long sB, long long sC, int nx, int ny, int ldc, int coloff)
{
    __shared__ __align__(16) unsigned short As[2][128 * 32];
    __shared__ __align__(16) unsigned short Bs[2][128 * 32];

    // XCD-aware block swizzle (nwg % 8 == 0 by launch config)
    const int nwg = gridDim.x;
    const int cpx = nwg >> 3;
    const int orig = blockIdx.x;
    const int wg = (orig & 7) * cpx + (orig >> 3);
    const int per = nx * ny;
    const int bz = wg / per, rem = wg - bz * per;
    const int by = rem / nx, bx = rem - by * nx;

    const int tid = threadIdx.x, lane = tid & 63;
    const int w = tid >> 6, wr = w >> 1, wc = w & 1;
    const unsigned short* A = Ap + (size_t)bz * sA + (size_t)by * 128 * DIM;
    const unsigned short* B = Bp + (size_t)bz * sB + (size_t)bx * 128 * DIM;
    f32x4 acc[4][4] = {};
    const int gr = tid >> 2, gs = (tid & 3) * 8;   // staging row / 16B slot

    // tile = 128 rows x 32 cols bf16 = 8KB; one GL16 sweep = 4KB -> two per operand
#define STAGE_TILE(buf, k0) do { \
        GL16(A + (size_t)gr * DIM + (k0) + gs, &As[buf][gr * 32 + gs]); \
        GL16(A + (size_t)(gr + 64) * DIM + (k0) + gs, &As[buf][(gr + 64) * 32 + gs]); \
        GL16(B + (size_t)gr * DIM + (k0) + gs, &Bs[buf][gr * 32 + gs]); \
        GL16(B + (size_t)(gr + 64) * DIM + (k0) + gs, &Bs[buf][(gr + 64) * 32 + gs]); \
    } while (0)

    STAGE_TILE(0, 0);
    const int NT = DIM / 32;           // 32 K-steps
    for (int t = 0; t < NT; ++t) {
        __syncthreads();               // drains stage of buf[t&1]; all reads of buf[(t-1)&1] retired
        if (t + 1 < NT) STAGE_TILE((t + 1) & 1, (t + 1) * 32);

        const unsigned short* as = As[t & 1];
        const unsigned short* bs = Bs[t & 1];
        bf16x8 a[4], b[4];
        const int ks = (lane >> 4) * 8;
#pragma unroll
        for (int m = 0; m < 4; ++m)
            a[m] = *(const bf16x8*)&as[(wr * 64 + m * 16 + (lane & 15)) * 32 + ks];
#pragma unroll
        for (int n = 0; n < 4; ++n)
            b[n] = *(const bf16x8*)&bs[(wc * 64 + n * 16 + (lane & 15)) * 32 + ks];
#pragma unroll
        for (int m = 0; m < 4; ++m)
#pragma unroll
            for (int n = 0; n < 4; ++n)
                acc[m][n] = __builtin_amdgcn_mfma_f32_16x16x32_bf16(a[m], b[n], acc[m][n], 0, 0, 0);
    }
#undef STAGE_TILE

    float* C = Cp + (size_t)bz * sC;
    const int rb = by * 128 + wr * 64 + ((lane >> 4) << 2);
    const int cb = coloff + bx * 128 + wc * 64 + (lane & 15);
#pragma unroll
    for (int m = 0; m < 4; ++m)
#pragma unroll
        for (int n = 0; n < 4; ++n)
#pragma unroll
            for (int j = 0; j < 4; ++j)
                C[(size_t)(rb + m * 16 + j) * ldc + cb + n * 16] = acc[m][n][j];
}

// ---------------------------------------------------------------------------
// Softmax over 1024-wide rows, single pass: cos in [-1,1] so constant shift
// 1.0 replaces the row-max pass. Writes fp32 G in-place (it IS an output)
// and a bf16 copy to ws for the downstream GEMM.
// ---------------------------------------------------------------------------
__global__ __launch_bounds__(256) void softmax_bf(
    float* __restrict__ G, unsigned short* __restrict__ Gb)
{
    __shared__ float reds[4];
    const long long row = blockIdx.x;
    float4* p = (float4*)(G + row * 1024);
    const int tid = threadIdx.x, lane = tid & 63, w = tid >> 6;
    float4 v = p[tid];
    float4 e;
    e.x = __expf(v.x - 1.0f); e.y = __expf(v.y - 1.0f);
    e.z = __expf(v.z - 1.0f); e.w = __expf(v.w - 1.0f);
    float s = e.x + e.y + e.z + e.w;
#pragma unroll
    for (int o = 1; o < 64; o <<= 1) s += __shfl_xor(s, o, 64);
    if (lane == 0) reds[w] = s;
    __syncthreads();
    s = reds[0] + reds[1] + reds[2] + reds[3];
    const float inv = 1.0f / s;
    e.x *= inv; e.y *= inv; e.z *= inv; e.w *= inv;
    p[tid] = e;
    ushort4 u;
    u.x = f2bf(e.x); u.y = f2bf(e.y); u.z = f2bf(e.z); u.w = f2bf(e.w);
    ((ushort4*)(Gb + row * 1024))[tid] = u;
}

// ---------------------------------------------------------------------------
extern "C" void kernel_launch(void* const* d_in, const int* in_sizes, int n_in,
                              void* d_out, int out_size, void* d_ws, size_t ws_size,
                              hipStream_t stream)
{
    const float* emb_s = (const float*)d_in[0];
    const float* emb_q = (const float*)d_in[1];
    float* out = (float*)d_out;
    float* aug_s = out;                                    // [8,1024,2048]
    float* aug_q = out + (size_t)BATCH * NS * 2 * DIM;     // [8,2048,2048]
    float* G_s   = aug_q + (size_t)BATCH * NQ * 2 * DIM;   // [8,1024,1024]
    float* G_q   = G_s + (size_t)BATCH * NS * NS;          // [8,2048,1024]

    // workspace: 16+32+16 MB bf16 buffers = 64 MB total
    unsigned short* supn = (unsigned short*)d_ws;                 // bf16 [8,1024,1024]
    unsigned short* qryn = supn + (size_t)BATCH * NS * DIM;       // bf16 [8,2048,1024]
    unsigned short* embT = qryn + (size_t)BATCH * NQ * DIM;       // bf16 [8,1024(d),1024(j)]
    // bf16 G copies REUSE supn/qryn (dead after the cos GEMMs; sizes match)
    unsigned short* Gs_bf = supn;
    unsigned short* Gq_bf = qryn;

    normalize_rows<<<BATCH * NS / 4, 256, 0, stream>>>(emb_s, aug_s, supn);
    normalize_rows<<<BATCH * NQ / 4, 256, 0, stream>>>(emb_q, aug_q, qryn);
    transpose_bf16<<<dim3(16, 16, BATCH), 256, 0, stream>>>(emb_s, embT);

    // cos matrices into the G output regions (softmaxed in-place next)
    gemm_bt<<<8 * 8 * BATCH, 256, 0, stream>>>(supn, supn, G_s,
        (long long)NS * DIM, (long long)NS * DIM, (long long)NS * NS, 8, 8, NS, 0);
    gemm_bt<<<8 * 16 * BATCH, 256, 0, stream>>>(qryn, supn, G_q,
        (long long)NQ * DIM, (long long)NS * DIM, (long long)NQ * NS, 8, 16, NS, 0);

    softmax_bf<<<BATCH * NS, 256, 0, stream>>>(G_s, Gs_bf);
    softmax_bf<<<BATCH * NQ, 256, 0, stream>>>(G_q, Gq_bf);

    // emb_task into augmented second halves (A = bf16 G, B = embT bf16)
    gemm_bt<<<8 * 8 * BATCH, 256, 0, stream>>>(Gs_bf, embT, aug_s,
        (long long)NS * NS, (long long)DIM * NS, (long long)NS * 2 * DIM, 8, 8, 2 * DIM, DIM);
    gemm_bt<<<8 * 16 * BATCH, 256, 0, stream>>>(Gq_bf, embT, aug_q,
        (long long)NQ * NS, (long long)DIM * NS, (long long)NQ * 2 * DIM, 8, 16, 2 * DIM, DIM);
}